// Round 1
// baseline (603.583 us; speedup 1.0000x reference)
//
#include <hip/hip_runtime.h>

// DEQ fully register-resident: out = relu^{(30)}(z Wz^T + inj) @ Wd^T + bd
//
// Each WAVE owns 16 batch rows and the FULL 128-wide hidden state:
//   D[n][m] = sum_k Wz[n][k] * z^T[k][m], n = 0..127 (8 MFMA tiles), m = l15.
// Wz lives in 128 regs/lane (unified VGPR+AGPR file). z is re-fed to the next
// iteration's B-operand entirely in-register:
//   D layout: lane(q,l) holds n = 16t + 4q + i  (i = reg 0..3)
//   B layout: lane(q,l) needs k = 32ks + 8q + j (j = 0..7)
//   => element j of frag[ks] comes from lane q_src=(2q+(j>>2))&3, tile
//      t = 2ks+(q>>1), reg i = j&3.  The t-parity split is v_permlane32_swap,
//      the A/B-source split is ds_swizzle xor-16, plus cndmask selects.
// No __shared__, no __syncthreads, no LDS bank conflicts.

typedef __attribute__((ext_vector_type(8))) __bf16 bf16x8;
typedef __attribute__((ext_vector_type(2))) __bf16 bf16x2;
typedef __attribute__((ext_vector_type(4))) float  floatx4;

#define MFMA16(a, b, c) __builtin_amdgcn_mfma_f32_16x16x32_bf16((a), (b), (c), 0, 0, 0)

static constexpr int kBsz = 262144;

__device__ __forceinline__ bf16x8 cvt_bf16x8(float4 a, float4 b) {
  bf16x8 r;
  r[0] = (__bf16)a.x; r[1] = (__bf16)a.y; r[2] = (__bf16)a.z; r[3] = (__bf16)a.w;
  r[4] = (__bf16)b.x; r[5] = (__bf16)b.y; r[6] = (__bf16)b.z; r[7] = (__bf16)b.w;
  return r;
}

__device__ __forceinline__ unsigned pk_relu2(float a, float b) {
  union { bf16x2 h; unsigned u; } x;
  x.h[0] = (__bf16)fmaxf(a, 0.0f);
  x.h[1] = (__bf16)fmaxf(b, 0.0f);
  return x.u;
}

union Frag { bf16x8 v; unsigned w[4]; };

// Build B-frag for k-chunk ks from packed z of tiles (2ks, 2ks+1).
// ulo/vlo = lo-words (regs i0,i1) of tiles 2ks / 2ks+1; uhi/vhi = hi-words.
__device__ __forceinline__ bf16x8 build_frag(unsigned ulo, unsigned vlo,
                                             unsigned uhi, unsigned vhi,
                                             bool qodd) {
  // after swap: u = {u.lo32, v.lo32}, v = {u.hi32, v.hi32}
  asm("v_permlane32_swap_b32 %0, %1" : "+v"(ulo), "+v"(vlo));
  asm("v_permlane32_swap_b32 %0, %1" : "+v"(uhi), "+v"(vhi));
  const unsigned c0 = qodd ? vlo : ulo;   // self-source word
  const unsigned d0 = qodd ? ulo : vlo;   // word the xor-16 partner needs
  const unsigned c1 = qodd ? vhi : uhi;
  const unsigned d1 = qodd ? uhi : vhi;
  const unsigned dx0 = __builtin_amdgcn_ds_swizzle((int)d0, 0x401F); // lane ^= 16
  const unsigned dx1 = __builtin_amdgcn_ds_swizzle((int)d1, 0x401F);
  Frag f;
  f.w[0] = qodd ? dx0 : c0;  // j=0,1 (A-source, regs i0,i1)
  f.w[1] = qodd ? dx1 : c1;  // j=2,3 (A-source, regs i2,i3)
  f.w[2] = qodd ? c0 : dx0;  // j=4,5 (B-source, regs i0,i1)
  f.w[3] = qodd ? c1 : dx1;  // j=6,7 (B-source, regs i2,i3)
  return f.v;
}

__global__ void __launch_bounds__(256) deq_fused(
    const float* __restrict__ x,    // [B,64]
    const float* __restrict__ Wz,   // [128,128]
    const float* __restrict__ Ux,   // [128,64]
    const float* __restrict__ bvec, // [128]
    const float* __restrict__ Wd,   // [64,128]
    const float* __restrict__ bd,   // [64]
    const int*  __restrict__ n_iters_p,
    float* __restrict__ out)        // [B,64]
{
  const int tid  = threadIdx.x;
  const int lane = tid & 63;
  const int wv   = tid >> 6;          // 0..3, independent waves
  const int l15  = lane & 15;
  const int quad = lane >> 4;         // 0..3
  const bool qodd = (quad & 1) != 0;
  const int  mrow = blockIdx.x * 64 + wv * 16 + l15;  // this lane's batch row
  const int  iters = *n_iters_p;

  // ---- inj[t] in C/D layout: reg i -> n = 16t + 4q + i, col m = l15 ----
  floatx4 inj[8];
#pragma unroll
  for (int t = 0; t < 8; ++t) {
    const float4 bv = *(const float4*)(bvec + 16 * t + 4 * quad);
    floatx4 v = {bv.x, bv.y, bv.z, bv.w};
    inj[t] = v;
  }
  {
    // x^T as B-frags (K=64 -> 2 k-chunks)
    bf16x8 bx[2];
#pragma unroll
    for (int ks = 0; ks < 2; ++ks) {
      const float4* p = (const float4*)(x + (size_t)mrow * 64 + 32 * ks + 8 * quad);
      bx[ks] = cvt_bf16x8(p[0], p[1]);
    }
#pragma unroll
    for (int t = 0; t < 8; ++t) {
#pragma unroll
      for (int ks = 0; ks < 2; ++ks) {
        const float4* p = (const float4*)(Ux + (16 * t + l15) * 64 + 32 * ks + 8 * quad);
        const bf16x8 a = cvt_bf16x8(p[0], p[1]);
        inj[t] = MFMA16(a, bx[ks], inj[t]);
      }
    }
  }

  // ---- Wz as A-frags, full 128x128, register/AGPR-resident (128 regs) ----
  bf16x8 awz[8][4];
#pragma unroll
  for (int t = 0; t < 8; ++t)
#pragma unroll
    for (int ks = 0; ks < 4; ++ks) {
      const float4* p = (const float4*)(Wz + (16 * t + l15) * 128 + 32 * ks + 8 * quad);
      awz[t][ks] = cvt_bf16x8(p[0], p[1]);
    }

  // ---- z1 = relu(inj) packed: lo = (i0,i1), hi = (i2,i3) per tile ----
  unsigned lo[8], hi[8];
#pragma unroll
  for (int t = 0; t < 8; ++t) {
    lo[t] = pk_relu2(inj[t][0], inj[t][1]);
    hi[t] = pk_relu2(inj[t][2], inj[t][3]);
  }

  // ---- fixed-point loop: zero LDS memory, zero barriers ----
  for (int it = 0; it < iters - 1; ++it) {
    floatx4 acc[8];
    {
      const bf16x8 f0 = build_frag(lo[0], lo[1], hi[0], hi[1], qodd);
#pragma unroll
      for (int t = 0; t < 8; ++t)
        acc[t] = MFMA16(awz[t][0], f0, inj[t]);   // C-in = inj, no copies
    }
#pragma unroll
    for (int ks = 1; ks < 4; ++ks) {
      const bf16x8 f = build_frag(lo[2 * ks], lo[2 * ks + 1],
                                  hi[2 * ks], hi[2 * ks + 1], qodd);
#pragma unroll
      for (int t = 0; t < 8; ++t)
        acc[t] = MFMA16(awz[t][ks], f, acc[t]);
    }
#pragma unroll
    for (int t = 0; t < 8; ++t) {
      lo[t] = pk_relu2(acc[t][0], acc[t][1]);
      hi[t] = pk_relu2(acc[t][2], acc[t][3]);
    }
  }

  // ---- decoder: D[o][m] = sum_k Wd[o][k] z^T[k][m] + bd ----
  bf16x8 bz[4];
#pragma unroll
  for (int ks = 0; ks < 4; ++ks)
    bz[ks] = build_frag(lo[2 * ks], lo[2 * ks + 1],
                        hi[2 * ks], hi[2 * ks + 1], qodd);
#pragma unroll
  for (int ot = 0; ot < 4; ++ot) {
    const float4 bv = *(const float4*)(bd + 16 * ot + 4 * quad);
    floatx4 acc = {bv.x, bv.y, bv.z, bv.w};
#pragma unroll
    for (int ks = 0; ks < 4; ++ks) {
      const float4* p = (const float4*)(Wd + (16 * ot + l15) * 128 + 32 * ks + 8 * quad);
      const bf16x8 a = cvt_bf16x8(p[0], p[1]);
      acc = MFMA16(a, bz[ks], acc);
    }
    float4 ov;
    ov.x = acc[0]; ov.y = acc[1]; ov.z = acc[2]; ov.w = acc[3];
    *(float4*)(out + (size_t)mrow * 64 + 16 * ot + 4 * quad) = ov;
  }
}

extern "C" void kernel_launch(void* const* d_in, const int* in_sizes, int n_in,
                              void* d_out, int out_size, void* d_ws, size_t ws_size,
                              hipStream_t stream) {
  const float* x  = (const float*)d_in[0];
  const float* Wz = (const float*)d_in[1];
  const float* Ux = (const float*)d_in[2];
  const float* b  = (const float*)d_in[3];
  const float* Wd = (const float*)d_in[4];
  const float* bd = (const float*)d_in[5];
  const int* n_it = (const int*)d_in[6];
  float* outp = (float*)d_out;
  (void)in_sizes; (void)n_in; (void)d_ws; (void)ws_size; (void)out_size;

  dim3 grid(kBsz / 64);  // 4096 blocks x 4 independent waves, 16 rows/wave
  deq_fused<<<grid, 256, 0, stream>>>(x, Wz, Ux, b, Wd, bd, n_it, outp);
}

// Round 2
// 403.247 us; speedup vs baseline: 1.4968x; 1.4968x over previous
//
#include <hip/hip_runtime.h>

// DEQ fused: out = relu^{(30)}(z Wz^T + inj) @ Wd^T + bd, inj = x Ux^T + b
//
// Round-0 structure (4 waves, n-split via LDS exchange, double buffer, one
// barrier/iter) with two upgrades:
//  1. 32x32x16 MFMA (faster rate than 16x16x32, half the instructions).
//  2. Unpadded [64][128] bf16 LDS tile with XOR swizzle elem ^= (m&7)<<3:
//     b128 reads hit all 32 banks once per 8-lane phase, b64 writes are
//     2-way (free) -> SQ_LDS_BANK_CONFLICT ~ 0.
//
// Layouts (32x32x16 bf16):
//   A[row][k]: row = lane&31, k = 8*(lane>>5)+j   (8 bf16 / lane)
//   B[k][col]: col = lane&31, k = 8*(lane>>5)+j
//   C/D:       col = lane&31, row = (reg&3) + 8*(reg>>2) + 4*(lane>>5)
// D reg groups of 4 are consecutive n -> packed b64 stores to z[m][n];
// B-frags read contiguous k -> b128 loads. No transpose anywhere.

typedef __attribute__((ext_vector_type(8)))  __bf16 bf16x8;
typedef __attribute__((ext_vector_type(4)))  __bf16 bf16x4;
typedef __attribute__((ext_vector_type(16))) float  floatx16;

#define MFMA32(a, b, c) __builtin_amdgcn_mfma_f32_32x32x16_bf16((a), (b), (c), 0, 0, 0)

static constexpr int kBsz = 262144;
static constexpr int kTM  = 64;   // batch rows per block

__device__ __forceinline__ bf16x8 cvt_bf16x8(float4 a, float4 b) {
  bf16x8 r;
  r[0] = (__bf16)a.x; r[1] = (__bf16)a.y; r[2] = (__bf16)a.z; r[3] = (__bf16)a.w;
  r[4] = (__bf16)b.x; r[5] = (__bf16)b.y; r[6] = (__bf16)b.z; r[7] = (__bf16)b.w;
  return r;
}

__global__ void __launch_bounds__(256) deq_fused(
    const float* __restrict__ x,    // [B,64]
    const float* __restrict__ Wz,   // [128,128]
    const float* __restrict__ Ux,   // [128,64]
    const float* __restrict__ bvec, // [128]
    const float* __restrict__ Wd,   // [64,128]
    const float* __restrict__ bd,   // [64]
    const int*  __restrict__ n_iters_p,
    float* __restrict__ out)        // [B,64]
{
  __shared__ __align__(16) __bf16 zl[2][kTM * 128];  // 32 KiB, swizzled

  const int tid  = threadIdx.x;
  const int lane = tid & 63;
  const int wv   = tid >> 6;   // 0..3
  const int wn   = wv & 1;     // n-half: hid units [64*wn, 64*wn+64)
  const int wm   = wv >> 1;    // m-half: rows [32*wm, 32*wm+32)
  const int l31  = lane & 31;
  const int hi   = lane >> 5;  // 0..1
  const int row0 = blockIdx.x * kTM;
  const int m    = 32 * wm + l31;       // local m row (0..63)
  const int msw  = (m & 7) << 3;        // XOR swizzle (bf16-element units)
  const int iters = *n_iters_p;

  // ---- inj[nt] in C/D layout: reg 4g+i -> n = 64wn+32nt+8g+4hi+i, col m ----
  floatx16 inj[2];
#pragma unroll
  for (int nt = 0; nt < 2; ++nt)
#pragma unroll
    for (int g = 0; g < 4; ++g) {
      const float4 bv = *(const float4*)(bvec + 64 * wn + 32 * nt + 8 * g + 4 * hi);
      inj[nt][4 * g + 0] = bv.x; inj[nt][4 * g + 1] = bv.y;
      inj[nt][4 * g + 2] = bv.z; inj[nt][4 * g + 3] = bv.w;
    }
  {
    // x^T as B-frags (K=64 -> 4 k-steps of 16)
    bf16x8 bx[4];
#pragma unroll
    for (int ks = 0; ks < 4; ++ks) {
      const float4* p = (const float4*)(x + (size_t)(row0 + m) * 64 + 16 * ks + 8 * hi);
      bx[ks] = cvt_bf16x8(p[0], p[1]);
    }
#pragma unroll
    for (int nt = 0; nt < 2; ++nt)
#pragma unroll
      for (int ks = 0; ks < 4; ++ks) {
        const float4* p = (const float4*)(Ux + (64 * wn + 32 * nt + l31) * 64 + 16 * ks + 8 * hi);
        inj[nt] = MFMA32(cvt_bf16x8(p[0], p[1]), bx[ks], inj[nt]);
      }
  }

  // ---- Wz as A-frags (iteration-invariant, 64 regs) ----
  bf16x8 awz[2][8];
#pragma unroll
  for (int nt = 0; nt < 2; ++nt)
#pragma unroll
    for (int ks = 0; ks < 8; ++ks) {
      const float4* p = (const float4*)(Wz + (64 * wn + 32 * nt + l31) * 128 + 16 * ks + 8 * hi);
      awz[nt][ks] = cvt_bf16x8(p[0], p[1]);
    }

  // ---- z1 = relu(inj) (z0 = 0) -> buffer 0 ----
#pragma unroll
  for (int nt = 0; nt < 2; ++nt)
#pragma unroll
    for (int g = 0; g < 4; ++g) {
      bf16x4 z4;
#pragma unroll
      for (int i = 0; i < 4; ++i) z4[i] = (__bf16)fmaxf(inj[nt][4 * g + i], 0.0f);
      const int n0 = 64 * wn + 32 * nt + 8 * g + 4 * hi;
      *(bf16x4*)&zl[0][m * 128 + (n0 ^ msw)] = z4;
    }

  // ---- fixed-point loop: 1 barrier per iteration (double buffer) ----
  int pb = 0;
  for (int t = 0; t < iters - 1; ++t) {
    __syncthreads();
    floatx16 acc[2];
    acc[0] = inj[0]; acc[1] = inj[1];
    {
      bf16x8 bz[4];
#pragma unroll
      for (int ks = 0; ks < 4; ++ks)
        bz[ks] = *(const bf16x8*)&zl[pb][m * 128 + ((16 * ks + 8 * hi) ^ msw)];
#pragma unroll
      for (int nt = 0; nt < 2; ++nt)
#pragma unroll
        for (int ks = 0; ks < 4; ++ks)
          acc[nt] = MFMA32(awz[nt][ks], bz[ks], acc[nt]);
    }
    {
      bf16x8 bz[4];
#pragma unroll
      for (int ks = 0; ks < 4; ++ks)
        bz[ks] = *(const bf16x8*)&zl[pb][m * 128 + ((16 * (ks + 4) + 8 * hi) ^ msw)];
#pragma unroll
      for (int nt = 0; nt < 2; ++nt)
#pragma unroll
        for (int ks = 0; ks < 4; ++ks)
          acc[nt] = MFMA32(awz[nt][ks + 4], bz[ks], acc[nt]);
    }
    const int nb = pb ^ 1;
#pragma unroll
    for (int nt = 0; nt < 2; ++nt)
#pragma unroll
      for (int g = 0; g < 4; ++g) {
        bf16x4 z4;
#pragma unroll
        for (int i = 0; i < 4; ++i) z4[i] = (__bf16)fmaxf(acc[nt][4 * g + i], 0.0f);
        const int n0 = 64 * wn + 32 * nt + 8 * g + 4 * hi;
        *(bf16x4*)&zl[nb][m * 128 + (n0 ^ msw)] = z4;
      }
    pb = nb;
  }
  __syncthreads();

  // ---- decoder: D[o][m] = sum_k Wd[o][k] Z^T[k][m] + bd, o-half = 32*wn ----
  floatx16 acc;
#pragma unroll
  for (int g = 0; g < 4; ++g) {
    const float4 bv = *(const float4*)(bd + 32 * wn + 8 * g + 4 * hi);
    acc[4 * g + 0] = bv.x; acc[4 * g + 1] = bv.y;
    acc[4 * g + 2] = bv.z; acc[4 * g + 3] = bv.w;
  }
#pragma unroll
  for (int ks = 0; ks < 8; ++ks) {
    const float4* p = (const float4*)(Wd + (32 * wn + l31) * 128 + 16 * ks + 8 * hi);
    const bf16x8 a = cvt_bf16x8(p[0], p[1]);
    const bf16x8 bzf = *(const bf16x8*)&zl[pb][m * 128 + ((16 * ks + 8 * hi) ^ msw)];
    acc = MFMA32(a, bzf, acc);
  }
#pragma unroll
  for (int g = 0; g < 4; ++g) {
    float4 ov;
    ov.x = acc[4 * g + 0]; ov.y = acc[4 * g + 1];
    ov.z = acc[4 * g + 2]; ov.w = acc[4 * g + 3];
    *(float4*)(out + (size_t)(row0 + m) * 64 + 32 * wn + 8 * g + 4 * hi) = ov;
  }
}

extern "C" void kernel_launch(void* const* d_in, const int* in_sizes, int n_in,
                              void* d_out, int out_size, void* d_ws, size_t ws_size,
                              hipStream_t stream) {
  const float* x  = (const float*)d_in[0];
  const float* Wz = (const float*)d_in[1];
  const float* Ux = (const float*)d_in[2];
  const float* b  = (const float*)d_in[3];
  const float* Wd = (const float*)d_in[4];
  const float* bd = (const float*)d_in[5];
  const int* n_it = (const int*)d_in[6];
  float* outp = (float*)d_out;
  (void)in_sizes; (void)n_in; (void)d_ws; (void)ws_size; (void)out_size;

  dim3 grid(kBsz / kTM);  // 4096 blocks
  deq_fused<<<grid, 256, 0, stream>>>(x, Wz, Ux, b, Wd, bd, n_it, outp);
}